// Round 2
// baseline (892.546 us; speedup 1.0000x reference)
//
#include <hip/hip_runtime.h>
#include <hip/hip_bf16.h>

// Problem dims (fixed by reference)
#define B_  256
#define T_  250
#define D_  700
#define H_  1024
#define O_  20
#define KP  704          // K padded to multiple of 32 (22 K-steps of BK=32)

typedef __attribute__((ext_vector_type(8))) short bf16x8;
typedef __attribute__((ext_vector_type(4))) float f32x4;

// async global->LDS, 16B per lane (LDS dest = wave-uniform base + lane*16)
__device__ __forceinline__ void gl_lds16(const void* g, void* l) {
    __builtin_amdgcn_global_load_lds(
        (const __attribute__((address_space(1))) unsigned int*)g,
        (__attribute__((address_space(3))) unsigned int*)l, 16, 0, 0);
}

// ---------------------------------------------------------------------------
// Kernel A: split fp32 -> bf16 hi/lo, zero-padding K from Kin to Kout.
// Each thread handles 8 consecutive columns of one row; interior chunks use
// float4 loads (row base is 16B-aligned for Kin=700: 2800 B = 175*16).
// ---------------------------------------------------------------------------
__global__ void split_convert(const float* __restrict__ src,
                              unsigned short* __restrict__ hi,
                              unsigned short* __restrict__ lo,
                              int M, int Kin, int Kout)
{
    int idx = blockIdx.x * blockDim.x + threadIdx.x;
    int chunks = Kout >> 3;
    int total = M * chunks;
    if (idx >= total) return;
    int m  = idx / chunks;
    int c  = idx - m * chunks;
    int d0 = c << 3;
    float x[8];
    if (d0 + 8 <= Kin) {
        const float4* p = (const float4*)(src + (long)m * Kin + d0);
        float4 v0 = p[0], v1 = p[1];
        x[0] = v0.x; x[1] = v0.y; x[2] = v0.z; x[3] = v0.w;
        x[4] = v1.x; x[5] = v1.y; x[6] = v1.z; x[7] = v1.w;
    } else {
#pragma unroll
        for (int e = 0; e < 8; ++e) {
            int d = d0 + e;
            x[e] = (d < Kin) ? src[(long)m * Kin + d] : 0.0f;
        }
    }
    unsigned short h8[8], l8[8];
#pragma unroll
    for (int e = 0; e < 8; ++e) {
        __hip_bfloat16 h = __float2bfloat16(x[e]);
        float hf = __bfloat162float(h);
        __hip_bfloat16 lv = __float2bfloat16(x[e] - hf);
        h8[e] = *(unsigned short*)&h;
        l8[e] = *(unsigned short*)&lv;
    }
    long ob = (long)m * Kout + d0;
    *(uint4*)(hi + ob) = *(uint4*)h8;
    *(uint4*)(lo + ob) = *(uint4*)l8;
}

// ---------------------------------------------------------------------------
// Kernel B: split-bf16 GEMM  C[m,n] = sum_k A[m,k]*B[n,k] + bias[n]
// (unchanged from round 1: 328 us, MfmaUtil 37% = m97-structure plateau)
// ---------------------------------------------------------------------------
__global__ __launch_bounds__(256, 2) void gemm_split(
    const unsigned short* __restrict__ Ahi, const unsigned short* __restrict__ Alo,
    const unsigned short* __restrict__ Bhi, const unsigned short* __restrict__ Blo,
    const float* __restrict__ bias, float* __restrict__ C)
{
    __shared__ __align__(16) unsigned short sAh[128 * 32];
    __shared__ __align__(16) unsigned short sAl[128 * 32];
    __shared__ __align__(16) unsigned short sBh[128 * 32];
    __shared__ __align__(16) unsigned short sBl[128 * 32];

    const int t    = threadIdx.x;
    const int nblk = blockIdx.x;   // 0..7   (N fastest -> A-tile reuse in L2/L3)
    const int mblk = blockIdx.y;   // 0..499
    const int wave = t >> 6, lane = t & 63;
    const int wr = wave >> 1, wc = wave & 1;

    f32x4 acc[4][4];
#pragma unroll
    for (int i = 0; i < 4; ++i)
#pragma unroll
        for (int j = 0; j < 4; ++j) acc[i][j] = (f32x4){0.f, 0.f, 0.f, 0.f};

    const long arow = (long)(mblk * 128 + (t >> 2)) * KP + (t & 3) * 8;
    const long brow = (long)(nblk * 128 + (t >> 2)) * KP + (t & 3) * 8;
    const int  l8   = t * 8;

    const int fr = lane & 15;
    const int fk = (lane >> 4) * 8;

    for (int ks = 0; ks < KP; ks += 32) {
        __syncthreads();
        gl_lds16(Ahi + arow + ks, &sAh[l8]);
        gl_lds16(Ahi + arow + 64 * KP + ks, &sAh[2048 + l8]);
        gl_lds16(Alo + arow + ks, &sAl[l8]);
        gl_lds16(Alo + arow + 64 * KP + ks, &sAl[2048 + l8]);
        gl_lds16(Bhi + brow + ks, &sBh[l8]);
        gl_lds16(Bhi + brow + 64 * KP + ks, &sBh[2048 + l8]);
        gl_lds16(Blo + brow + ks, &sBl[l8]);
        gl_lds16(Blo + brow + 64 * KP + ks, &sBl[2048 + l8]);
        __syncthreads();

        bf16x8 ah[4], al[4], bh[4], bl[4];
#pragma unroll
        for (int i = 0; i < 4; ++i) {
            ah[i] = *(const bf16x8*)&sAh[(wr * 64 + i * 16 + fr) * 32 + fk];
            al[i] = *(const bf16x8*)&sAl[(wr * 64 + i * 16 + fr) * 32 + fk];
            bh[i] = *(const bf16x8*)&sBh[(wc * 64 + i * 16 + fr) * 32 + fk];
            bl[i] = *(const bf16x8*)&sBl[(wc * 64 + i * 16 + fr) * 32 + fk];
        }
#pragma unroll
        for (int i = 0; i < 4; ++i)
#pragma unroll
            for (int j = 0; j < 4; ++j)
                acc[i][j] = __builtin_amdgcn_mfma_f32_16x16x32_bf16(ah[i], bh[j], acc[i][j], 0, 0, 0);
#pragma unroll
        for (int i = 0; i < 4; ++i)
#pragma unroll
            for (int j = 0; j < 4; ++j)
                acc[i][j] = __builtin_amdgcn_mfma_f32_16x16x32_bf16(ah[i], bl[j], acc[i][j], 0, 0, 0);
#pragma unroll
        for (int i = 0; i < 4; ++i)
#pragma unroll
            for (int j = 0; j < 4; ++j)
                acc[i][j] = __builtin_amdgcn_mfma_f32_16x16x32_bf16(al[i], bh[j], acc[i][j], 0, 0, 0);
    }

    const int r0 = mblk * 128 + wr * 64 + (lane >> 4) * 4;
    const int c0 = nblk * 128 + wc * 64 + (lane & 15);
#pragma unroll
    for (int j = 0; j < 4; ++j) {
        int col = c0 + j * 16;
        float bv = bias[col];
#pragma unroll
        for (int i = 0; i < 4; ++i) {
            int row = r0 + i * 16;
#pragma unroll
            for (int r = 0; r < 4; ++r)
                C[(long)(row + r) * H_ + col] = acc[i][j][r] + bv;
        }
    }
}

// ---------------------------------------------------------------------------
// Kernel C: sequential LIF scan, rewritten.
//  - One block (256 threads) per batch row; thread (wave w, lane l) owns
//    neurons h = e*256 + w*64 + l, e=0..3 (so __ballot of slot e in wave w is
//    exactly uint64 #q (q = e*4+w) of the bit-packed spike vector: bit r of
//    sbits[q] = spike of h = 64q + r).
//  - Spikes exchanged as 16 uint64 (128 B) via ballot; consumer lane l reads
//    sbits[l>>2] (4-lane broadcast, conflict-free) and unpacks bits for its
//    16 W2 columns h = 16l..16l+15.
//  - W2 in registers: wave w owns outputs 5w..5w+4, lane owns 16 columns.
//  - ONE barrier per timestep: sbits and sd2 double-buffered by ts&1; wave0
//    consumes d2(ts-1) after barrier(ts) while waves 1-3 run ahead.
// ---------------------------------------------------------------------------
__global__ __launch_bounds__(256, 1) void snn_scan(
    const float* __restrict__ d1,   // [B*T, H]
    const float* __restrict__ tau1, const float* __restrict__ W2,
    const float* __restrict__ b2,   const float* __restrict__ tau2,
    float* __restrict__ out)
{
    __shared__ unsigned long long sbits[2][16];
    __shared__ float sd2[2][20];

    const int b = blockIdx.x;
    const int t = threadIdx.x;
    const int wave = t >> 6, lane = t & 63;
    const int hb = wave * 64 + lane;          // base neuron (e=0)

    // layer-1 per-neuron state (stride-256 ownership)
    float a1[4], om1[4], mem1[4] = {0, 0, 0, 0}, spk[4] = {0, 0, 0, 0};
#pragma unroll
    for (int e = 0; e < 4; ++e) {
        float tv = tau1[e * 256 + hb];
        a1[e]  = 1.0f / (1.0f + __expf(-tv));
        om1[e] = 1.0f - a1[e];
    }

    // W2 fragment in registers: 5 outputs x 16 columns (cols 16l..16l+15)
    float w2r[5][16];
#pragma unroll
    for (int oo = 0; oo < 5; ++oo)
#pragma unroll
        for (int q = 0; q < 4; ++q)
            *(float4*)&w2r[oo][4 * q] =
                *(const float4*)&W2[(wave * 5 + oo) * H_ + lane * 16 + 4 * q];

    // readout state (wave 0, lanes 0..19)
    float mem2 = 0.f, accv = 0.f, a2 = 0.f, om2 = 0.f, b2v = 0.f;
    if (wave == 0 && lane < O_) {
        float tv = tau2[lane];
        a2 = 1.0f / (1.0f + __expf(-tv));
        om2 = 1.0f - a2;
        b2v = b2[lane];
    }

    const float* drow = d1 + (long)b * T_ * H_ + hb;
    float c0 = drow[0], c1 = drow[256], c2 = drow[512], c3 = drow[768];

    for (int ts = 0; ts < T_; ++ts) {
        // prefetch next timestep's d1 slice
        float n0 = 0.f, n1 = 0.f, n2 = 0.f, n3 = 0.f;
        if (ts + 1 < T_) {
            const float* nr = drow + (long)(ts + 1) * H_;
            n0 = nr[0]; n1 = nr[256]; n2 = nr[512]; n3 = nr[768];
        }

        // LIF layer 1 (soft reset with own previous spike)
        mem1[0] = mem1[0] * a1[0] + om1[0] * c0 - spk[0];
        mem1[1] = mem1[1] * a1[1] + om1[1] * c1 - spk[1];
        mem1[2] = mem1[2] * a1[2] + om1[2] * c2 - spk[2];
        mem1[3] = mem1[3] * a1[3] + om1[3] * c3 - spk[3];
        spk[0] = (mem1[0] > 1.0f) ? 1.0f : 0.0f;
        spk[1] = (mem1[1] > 1.0f) ? 1.0f : 0.0f;
        spk[2] = (mem1[2] > 1.0f) ? 1.0f : 0.0f;
        spk[3] = (mem1[3] > 1.0f) ? 1.0f : 0.0f;

        unsigned long long m0 = __ballot(spk[0] > 0.f);
        unsigned long long m1 = __ballot(spk[1] > 0.f);
        unsigned long long m2 = __ballot(spk[2] > 0.f);
        unsigned long long m3 = __ballot(spk[3] > 0.f);
        const int p = ts & 1;
        if (lane == 0) {
            sbits[p][0 + wave]  = m0;
            sbits[p][4 + wave]  = m1;
            sbits[p][8 + wave]  = m2;
            sbits[p][12 + wave] = m3;
        }
        __syncthreads();   // the ONLY barrier per timestep

        // masked dot: d2 partials for outputs 5w..5w+4 over columns 16l..16l+15
        unsigned long long bw = sbits[p][lane >> 2];
        unsigned int bits = (unsigned int)(bw >> ((lane & 3) * 16)) & 0xFFFFu;
        float pa[5] = {0.f, 0.f, 0.f, 0.f, 0.f};
#pragma unroll
        for (int j = 0; j < 16; ++j) {
            float f = (bits >> j) & 1u ? 1.0f : 0.0f;
#pragma unroll
            for (int oo = 0; oo < 5; ++oo)
                pa[oo] = fmaf(f, w2r[oo][j], pa[oo]);
        }
#pragma unroll
        for (int m = 1; m < 64; m <<= 1)
#pragma unroll
            for (int oo = 0; oo < 5; ++oo)
                pa[oo] += __shfl_xor(pa[oo], m, 64);
        if (lane == 0) {
#pragma unroll
            for (int oo = 0; oo < 5; ++oo) sd2[p][wave * 5 + oo] = pa[oo];
        }

        // deferred readout/softmax for ts-1 (overlaps waves 1-3's next LIF)
        if (wave == 0 && ts > 0) {
            int q = ts - 1, pp = q & 1;
            if (lane < O_) {
                float d2v = sd2[pp][lane] + b2v;
                mem2 = mem2 * a2 + om2 * d2v;
            }
            float mv = (lane < O_) ? mem2 : -3e38f;
#pragma unroll
            for (int m = 1; m < 64; m <<= 1)
                mv = fmaxf(mv, __shfl_xor(mv, m, 64));
            float ev = (lane < O_) ? __expf(mem2 - mv) : 0.f;
            float sum = ev;
#pragma unroll
            for (int m = 1; m < 64; m <<= 1)
                sum += __shfl_xor(sum, m, 64);
            if (q > 10 && lane < O_) accv += ev / sum;
        }

        c0 = n0; c1 = n1; c2 = n2; c3 = n3;
    }

    // tail: process d2(T-1)
    __syncthreads();
    if (wave == 0) {
        int q = T_ - 1, pp = q & 1;
        if (lane < O_) {
            float d2v = sd2[pp][lane] + b2v;
            mem2 = mem2 * a2 + om2 * d2v;
        }
        float mv = (lane < O_) ? mem2 : -3e38f;
#pragma unroll
        for (int m = 1; m < 64; m <<= 1)
            mv = fmaxf(mv, __shfl_xor(mv, m, 64));
        float ev = (lane < O_) ? __expf(mem2 - mv) : 0.f;
        float sum = ev;
#pragma unroll
        for (int m = 1; m < 64; m <<= 1)
            sum += __shfl_xor(sum, m, 64);
        if (lane < O_) {
            accv += ev / sum;      // q = 249 > 10 always
            out[b * O_ + lane] = accv;
        }
    }
}

// ---------------------------------------------------------------------------
extern "C" void kernel_launch(void* const* d_in, const int* in_sizes, int n_in,
                              void* d_out, int out_size, void* d_ws, size_t ws_size,
                              hipStream_t stream)
{
    const float* X    = (const float*)d_in[0];   // [B,T,D]
    const float* W1   = (const float*)d_in[1];   // [H,D]
    const float* b1   = (const float*)d_in[2];   // [H]
    const float* tau1 = (const float*)d_in[3];   // [H]
    const float* W2   = (const float*)d_in[4];   // [O,H]
    const float* b2   = (const float*)d_in[5];   // [O]
    const float* tau2 = (const float*)d_in[6];   // [O]
    float* out = (float*)d_out;

    const long M = (long)B_ * T_;                // 64000
    unsigned short* Xhi  = (unsigned short*)d_ws;
    unsigned short* Xlo  = Xhi + M * KP;
    unsigned short* W1hi = Xlo + M * KP;
    unsigned short* W1lo = W1hi + (long)H_ * KP;
    float* d1 = (float*)(W1lo + (long)H_ * KP);  // [M, H] fp32
    // total ws: 2*M*KP*2 + 2*H*KP*2 + M*H*4 = ~425 MiB

    // 1. split conversions
    {
        int chunks = (int)M * (KP / 8);          // 5,632,000
        split_convert<<<(chunks + 255) / 256, 256, 0, stream>>>(X, Xhi, Xlo, (int)M, D_, KP);
    }
    {
        int chunks = H_ * (KP / 8);              // 90,112
        split_convert<<<(chunks + 255) / 256, 256, 0, stream>>>(W1, W1hi, W1lo, H_, D_, KP);
    }

    // 2. d1 = X @ W1^T + b1   (split-bf16 MFMA, ~fp32 accuracy)
    {
        dim3 grid(H_ / 128, (int)(M / 128));     // (8, 500), N fastest
        gemm_split<<<grid, 256, 0, stream>>>(Xhi, Xlo, W1hi, W1lo, b1, d1);
    }

    // 3. sequential scan, one block per batch row
    snn_scan<<<B_, 256, 0, stream>>>(d1, tau1, W2, b2, tau2, out);
}

// Round 3
// 889.516 us; speedup vs baseline: 1.0034x; 1.0034x over previous
//
#include <hip/hip_runtime.h>
#include <hip/hip_bf16.h>

// Problem dims (fixed by reference)
#define B_  256
#define T_  250
#define D_  700
#define H_  1024
#define O_  20
#define KP  704          // K padded to multiple of 32 (22 K-steps of BK=32)

typedef __attribute__((ext_vector_type(8))) short bf16x8;
typedef __attribute__((ext_vector_type(4))) float f32x4;

// barrier that waits LDS only — leaves global loads in flight (CK idiom).
// "memory" clobber stops compiler reordering of memory ops across it.
#define BAR_LGKM() asm volatile("s_waitcnt lgkmcnt(0)\n\ts_barrier" ::: "memory")

// async global->LDS, 16B per lane (LDS dest = wave-uniform base + lane*16)
__device__ __forceinline__ void gl_lds16(const void* g, void* l) {
    __builtin_amdgcn_global_load_lds(
        (const __attribute__((address_space(1))) unsigned int*)g,
        (__attribute__((address_space(3))) unsigned int*)l, 16, 0, 0);
}

// ---------------------------------------------------------------------------
// Kernel A: split fp32 -> bf16 hi/lo with zero-pad (now only used for W1,
// 1024x700 -> 1024x704: ~3 us).
// ---------------------------------------------------------------------------
__global__ void split_convert(const float* __restrict__ src,
                              unsigned short* __restrict__ hi,
                              unsigned short* __restrict__ lo,
                              int M, int Kin, int Kout)
{
    int idx = blockIdx.x * blockDim.x + threadIdx.x;
    int chunks = Kout >> 3;
    int total = M * chunks;
    if (idx >= total) return;
    int m  = idx / chunks;
    int c  = idx - m * chunks;
    int d0 = c << 3;
    float x[8];
#pragma unroll
    for (int e = 0; e < 8; ++e) {
        int d = d0 + e;
        x[e] = (d < Kin) ? src[(long)m * Kin + d] : 0.0f;
    }
    unsigned short h8[8], l8[8];
#pragma unroll
    for (int e = 0; e < 8; ++e) {
        __hip_bfloat16 h = __float2bfloat16(x[e]);
        float hf = __bfloat162float(h);
        __hip_bfloat16 lv = __float2bfloat16(x[e] - hf);
        h8[e] = *(unsigned short*)&h;
        l8[e] = *(unsigned short*)&lv;
    }
    long ob = (long)m * Kout + d0;
    *(uint4*)(hi + ob) = *(uint4*)h8;
    *(uint4*)(lo + ob) = *(uint4*)l8;
}

// ---------------------------------------------------------------------------
// Kernel B: fused split-bf16 GEMM  C[m,n] = sum_k X[m,k]*W1[n,k] + bias[n]
// A-side stages RAW FP32 X tiles (same bytes as hi+lo bf16) and converts
// hi/lo in-register after the LDS read — split_X kernel eliminated.
// A-tile LDS uses an XOR chunk swizzle (slot = c ^ (row&7)) so the fp32
// fragment reads stay 2-way-conflict (fp32 row stride 128 B would otherwise
// be 16-way). B-side (W1hi/W1lo, K-padded to 704 with ZEROS — relied on to
// kill the k=700..703 garbage columns) unchanged from round 1.
// ---------------------------------------------------------------------------
__global__ __launch_bounds__(256, 2) void gemm_fused(
    const float* __restrict__ X,
    const unsigned short* __restrict__ Bhi, const unsigned short* __restrict__ Blo,
    const float* __restrict__ bias, float* __restrict__ C)
{
    __shared__ __align__(16) float          sX [128 * 32];  // 16 KB, swizzled
    __shared__ __align__(16) unsigned short sBh[128 * 32];  //  8 KB
    __shared__ __align__(16) unsigned short sBl[128 * 32];  //  8 KB

    const int t    = threadIdx.x;
    const int nblk = blockIdx.x;   // 0..7   (N fastest -> A-tile reuse in L2/L3)
    const int mblk = blockIdx.y;   // 0..499
    const int wave = t >> 6, lane = t & 63;
    const int wr = wave >> 1, wc = wave & 1;

    f32x4 acc[4][4];
#pragma unroll
    for (int i = 0; i < 4; ++i)
#pragma unroll
        for (int j = 0; j < 4; ++j) acc[i][j] = (f32x4){0.f, 0.f, 0.f, 0.f};

    // --- A staging: thread t -> row r0 = t>>3 (+32/issue), stored slot t&7,
    //     logical col chunk cl/4 = (t&7) ^ (r0&7). 16 B = 4 floats per lane.
    const int r0 = t >> 3;
    const int cl = (((t & 7) ^ (r0 & 7)) << 2);            // logical col off 0..28
    const float* ap = X + (long)(mblk * 128 + r0) * D_;    // row stride 700!
    // --- B staging (bf16): thread t -> row t>>2, 8 elems at (t&3)*8
    const long brow = (long)(nblk * 128 + (t >> 2)) * KP + (t & 3) * 8;
    const int  l8   = t * 8;

    const int fr = lane & 15;
    const int fk = (lane >> 4) * 8;

    // A-fragment LDS float offsets (swizzled), constant across K-steps
    int aoff[4][2];
#pragma unroll
    for (int i = 0; i < 4; ++i) {
        int R  = wr * 64 + i * 16 + fr;
        int c0 = (lane >> 4) * 2;                          // even chunk
        aoff[i][0] = R * 32 + (((c0    ) ^ (R & 7)) << 2);
        aoff[i][1] = R * 32 + (((c0 + 1) ^ (R & 7)) << 2);
    }

    for (int ks = 0; ks < KP; ks += 32) {
        // clamp the k=700..703 tail chunk into valid X (values killed by B=0)
        int col = ks + cl;
        if (col >= 697) col = ks + 24;
        __syncthreads();
        gl_lds16(ap + col,               &sX[t * 4]);
        gl_lds16(ap + 32 * D_ + col,     &sX[1024 + t * 4]);
        gl_lds16(ap + 64 * D_ + col,     &sX[2048 + t * 4]);
        gl_lds16(ap + 96 * D_ + col,     &sX[3072 + t * 4]);
        gl_lds16(Bhi + brow + ks,            &sBh[l8]);
        gl_lds16(Bhi + brow + 64 * KP + ks,  &sBh[2048 + l8]);
        gl_lds16(Blo + brow + ks,            &sBl[l8]);
        gl_lds16(Blo + brow + 64 * KP + ks,  &sBl[2048 + l8]);
        __syncthreads();

        bf16x8 ah[4], al[4], bh[4], bl[4];
#pragma unroll
        for (int i = 0; i < 4; ++i) {
            float4 xa = *(const float4*)&sX[aoff[i][0]];
            float4 xb = *(const float4*)&sX[aoff[i][1]];
            float xf[8] = {xa.x, xa.y, xa.z, xa.w, xb.x, xb.y, xb.z, xb.w};
            short h8[8], l8v[8];
#pragma unroll
            for (int e = 0; e < 8; ++e) {
                __hip_bfloat16 h = __float2bfloat16(xf[e]);
                float hf = __bfloat162float(h);
                __hip_bfloat16 lv = __float2bfloat16(xf[e] - hf);
                h8[e]  = *(short*)&h;
                l8v[e] = *(short*)&lv;
            }
            ah[i] = *(bf16x8*)h8;
            al[i] = *(bf16x8*)l8v;
            bh[i] = *(const bf16x8*)&sBh[(wc * 64 + i * 16 + fr) * 32 + fk];
            bl[i] = *(const bf16x8*)&sBl[(wc * 64 + i * 16 + fr) * 32 + fk];
        }
#pragma unroll
        for (int i = 0; i < 4; ++i)
#pragma unroll
            for (int j = 0; j < 4; ++j)
                acc[i][j] = __builtin_amdgcn_mfma_f32_16x16x32_bf16(ah[i], bh[j], acc[i][j], 0, 0, 0);
#pragma unroll
        for (int i = 0; i < 4; ++i)
#pragma unroll
            for (int j = 0; j < 4; ++j)
                acc[i][j] = __builtin_amdgcn_mfma_f32_16x16x32_bf16(ah[i], bl[j], acc[i][j], 0, 0, 0);
#pragma unroll
        for (int i = 0; i < 4; ++i)
#pragma unroll
            for (int j = 0; j < 4; ++j)
                acc[i][j] = __builtin_amdgcn_mfma_f32_16x16x32_bf16(al[i], bh[j], acc[i][j], 0, 0, 0);
    }

    // epilogue: C/D layout col=lane&15, row=(lane>>4)*4+reg  [m89-verified]
    const int rr0 = mblk * 128 + wr * 64 + (lane >> 4) * 4;
    const int cc0 = nblk * 128 + wc * 64 + (lane & 15);
#pragma unroll
    for (int j = 0; j < 4; ++j) {
        int colj = cc0 + j * 16;
        float bv = bias[colj];
#pragma unroll
        for (int i = 0; i < 4; ++i) {
            int row = rr0 + i * 16;
#pragma unroll
            for (int r = 0; r < 4; ++r)
                C[(long)(row + r) * H_ + colj] = acc[i][j][r] + bv;
        }
    }
}

// ---------------------------------------------------------------------------
// Kernel C: sequential LIF scan.
//  - One block (256 thr) per batch row; thread (w,l) owns h = e*256+w*64+l.
//  - Spikes exchanged as 16 uint64 via __ballot (word q=e*4+w, bit=lane).
//  - W2 in registers: wave w owns outputs 5w..5w+4, lane owns 16 columns.
//  - BAR_LGKM barriers (LDS-wait only!) so the 4-deep d1 prefetch ring stays
//    in flight across timesteps — the round-2 scan was latency-bound on the
//    compiler's vmcnt(0) drain at every __syncthreads.
// ---------------------------------------------------------------------------
__global__ __launch_bounds__(256, 1) void snn_scan(
    const float* __restrict__ d1,   // [B*T, H]
    const float* __restrict__ tau1, const float* __restrict__ W2,
    const float* __restrict__ b2,   const float* __restrict__ tau2,
    float* __restrict__ out)
{
    __shared__ unsigned long long sbits[2][16];
    __shared__ float sd2[2][20];

    const int b = blockIdx.x;
    const int t = threadIdx.x;
    const int wave = t >> 6, lane = t & 63;
    const int hb = wave * 64 + lane;          // base neuron (e=0)

    float a1[4], om1[4], mem1[4] = {0, 0, 0, 0}, spk[4] = {0, 0, 0, 0};
#pragma unroll
    for (int e = 0; e < 4; ++e) {
        float tv = tau1[e * 256 + hb];
        a1[e]  = 1.0f / (1.0f + __expf(-tv));
        om1[e] = 1.0f - a1[e];
    }

    float w2r[5][16];
#pragma unroll
    for (int oo = 0; oo < 5; ++oo)
#pragma unroll
        for (int q = 0; q < 4; ++q)
            *(float4*)&w2r[oo][4 * q] =
                *(const float4*)&W2[(wave * 5 + oo) * H_ + lane * 16 + 4 * q];

    float mem2 = 0.f, accv = 0.f, a2 = 0.f, om2 = 0.f, b2v = 0.f;
    if (wave == 0 && lane < O_) {
        float tv = tau2[lane];
        a2 = 1.0f / (1.0f + __expf(-tv));
        om2 = 1.0f - a2;
        b2v = b2[lane];
    }

    const float* dbase = d1 + (long)b * T_ * H_ + hb;
    // 4-deep prefetch ring
    float4 p0, p1, p2, p3;
    {
        const float* r;
        r = dbase;              p0 = make_float4(r[0], r[256], r[512], r[768]);
        r = dbase + 1L * H_;    p1 = make_float4(r[0], r[256], r[512], r[768]);
        r = dbase + 2L * H_;    p2 = make_float4(r[0], r[256], r[512], r[768]);
        r = dbase + 3L * H_;    p3 = make_float4(r[0], r[256], r[512], r[768]);
    }

    for (int ts = 0; ts < T_; ++ts) {
        float4 cur = p0;
        p0 = p1; p1 = p2; p2 = p3;
        if (ts + 4 < T_) {
            const float* r = dbase + (long)(ts + 4) * H_;
            p3 = make_float4(r[0], r[256], r[512], r[768]);
        }

        // LIF layer 1 (soft reset with own previous spike)
        mem1[0] = mem1[0] * a1[0] + om1[0] * cur.x - spk[0];
        mem1[1] = mem1[1] * a1[1] + om1[1] * cur.y - spk[1];
        mem1[2] = mem1[2] * a1[2] + om1[2] * cur.z - spk[2];
        mem1[3] = mem1[3] * a1[3] + om1[3] * cur.w - spk[3];
        spk[0] = (mem1[0] > 1.0f) ? 1.0f : 0.0f;
        spk[1] = (mem1[1] > 1.0f) ? 1.0f : 0.0f;
        spk[2] = (mem1[2] > 1.0f) ? 1.0f : 0.0f;
        spk[3] = (mem1[3] > 1.0f) ? 1.0f : 0.0f;

        unsigned long long m0 = __ballot(spk[0] > 0.f);
        unsigned long long m1 = __ballot(spk[1] > 0.f);
        unsigned long long m2 = __ballot(spk[2] > 0.f);
        unsigned long long m3 = __ballot(spk[3] > 0.f);
        const int p = ts & 1;
        if (lane == 0) {
            sbits[p][0 + wave]  = m0;
            sbits[p][4 + wave]  = m1;
            sbits[p][8 + wave]  = m2;
            sbits[p][12 + wave] = m3;
        }
        BAR_LGKM();   // LDS-wait-only barrier: d1 prefetches stay in flight

        unsigned long long bw = sbits[p][lane >> 2];
        unsigned int bits = (unsigned int)(bw >> ((lane & 3) * 16)) & 0xFFFFu;
        float pa[5] = {0.f, 0.f, 0.f, 0.f, 0.f};
#pragma unroll
        for (int j = 0; j < 16; ++j) {
            float f = (bits >> j) & 1u ? 1.0f : 0.0f;
#pragma unroll
            for (int oo = 0; oo < 5; ++oo)
                pa[oo] = fmaf(f, w2r[oo][j], pa[oo]);
        }
#pragma unroll
        for (int m = 1; m < 64; m <<= 1)
#pragma unroll
            for (int oo = 0; oo < 5; ++oo)
                pa[oo] += __shfl_xor(pa[oo], m, 64);
        if (lane == 0) {
#pragma unroll
            for (int oo = 0; oo < 5; ++oo) sd2[p][wave * 5 + oo] = pa[oo];
        }

        // deferred readout/softmax for ts-1 (overlaps waves 1-3 running ahead)
        if (wave == 0 && ts > 0) {
            int q = ts - 1, pp = q & 1;
            if (lane < O_) {
                float d2v = sd2[pp][lane] + b2v;
                mem2 = mem2 * a2 + om2 * d2v;
            }
            float mv = (lane < O_) ? mem2 : -3e38f;
#pragma unroll
            for (int m = 1; m < 64; m <<= 1)
                mv = fmaxf(mv, __shfl_xor(mv, m, 64));
            float ev = (lane < O_) ? __expf(mem2 - mv) : 0.f;
            float sum = ev;
#pragma unroll
            for (int m = 1; m < 64; m <<= 1)
                sum += __shfl_xor(sum, m, 64);
            if (q > 10 && lane < O_) accv += ev / sum;
        }
    }

    // tail: process d2(T-1)
    __syncthreads();
    if (wave == 0) {
        int q = T_ - 1, pp = q & 1;
        if (lane < O_) {
            float d2v = sd2[pp][lane] + b2v;
            mem2 = mem2 * a2 + om2 * d2v;
        }
        float mv = (lane < O_) ? mem2 : -3e38f;
#pragma unroll
        for (int m = 1; m < 64; m <<= 1)
            mv = fmaxf(mv, __shfl_xor(mv, m, 64));
        float ev = (lane < O_) ? __expf(mem2 - mv) : 0.f;
        float sum = ev;
#pragma unroll
        for (int m = 1; m < 64; m <<= 1)
            sum += __shfl_xor(sum, m, 64);
        if (lane < O_) {
            accv += ev / sum;      // q = 249 > 10 always
            out[b * O_ + lane] = accv;
        }
    }
}

// ---------------------------------------------------------------------------
extern "C" void kernel_launch(void* const* d_in, const int* in_sizes, int n_in,
                              void* d_out, int out_size, void* d_ws, size_t ws_size,
                              hipStream_t stream)
{
    const float* X    = (const float*)d_in[0];   // [B,T,D]
    const float* W1   = (const float*)d_in[1];   // [H,D]
    const float* b1   = (const float*)d_in[2];   // [H]
    const float* tau1 = (const float*)d_in[3];   // [H]
    const float* W2   = (const float*)d_in[4];   // [O,H]
    const float* b2   = (const float*)d_in[5];   // [O]
    const float* tau2 = (const float*)d_in[6];   // [O]
    float* out = (float*)d_out;

    const long M = (long)B_ * T_;                // 64000
    unsigned short* W1hi = (unsigned short*)d_ws;
    unsigned short* W1lo = W1hi + (long)H_ * KP;
    float* d1 = (float*)(W1lo + (long)H_ * KP);  // [M, H] fp32
    // total ws: 2*H*KP*2 + M*H*4 ~= 265 MiB

    // 1. split W1 only (X conversion fused into the GEMM)
    {
        int chunks = H_ * (KP / 8);              // 90,112
        split_convert<<<(chunks + 255) / 256, 256, 0, stream>>>(W1, W1hi, W1lo, H_, D_, KP);
    }

    // 2. d1 = X @ W1^T + b1   (fused split-bf16 MFMA, ~fp32 accuracy)
    {
        dim3 grid(H_ / 128, (int)(M / 128));     // (8, 500), N fastest
        gemm_fused<<<grid, 256, 0, stream>>>(X, W1hi, W1lo, b1, d1);
    }

    // 3. sequential scan, one block per batch row
    snn_scan<<<B_, 256, 0, stream>>>(d1, tau1, W2, b2, tau2, out);
}

// Round 4
// 807.290 us; speedup vs baseline: 1.1056x; 1.1019x over previous
//
#include <hip/hip_runtime.h>
#include <hip/hip_bf16.h>

// Problem dims (fixed by reference)
#define B_  256
#define T_  250
#define D_  700
#define H_  1024
#define O_  20
#define KP  704          // K padded to multiple of 32 (22 K-steps of BK=32)
#define M_  64000        // B_*T_

typedef __attribute__((ext_vector_type(8))) short bf16x8;
typedef __attribute__((ext_vector_type(4))) float f32x4;

// async global->LDS, 16B per lane (LDS dest = wave-uniform base + lane*16)
__device__ __forceinline__ void gl_lds16(const void* g, void* l) {
    __builtin_amdgcn_global_load_lds(
        (const __attribute__((address_space(1))) unsigned int*)g,
        (__attribute__((address_space(3))) unsigned int*)l, 16, 0, 0);
}

// ---------------------------------------------------------------------------
// Kernel A: split fp32 -> bf16 hi/lo, zero-padding K from Kin to Kout.
// (round-1 version: measured-good; used for both X and W1)
// ---------------------------------------------------------------------------
__global__ void split_convert(const float* __restrict__ src,
                              unsigned short* __restrict__ hi,
                              unsigned short* __restrict__ lo,
                              int M, int Kin, int Kout)
{
    int idx = blockIdx.x * blockDim.x + threadIdx.x;
    int chunks = Kout >> 3;
    int total = M * chunks;
    if (idx >= total) return;
    int m  = idx / chunks;
    int c  = idx - m * chunks;
    int d0 = c << 3;
    float x[8];
    if (d0 + 8 <= Kin) {
        const float4* p = (const float4*)(src + (long)m * Kin + d0);
        float4 v0 = p[0], v1 = p[1];
        x[0] = v0.x; x[1] = v0.y; x[2] = v0.z; x[3] = v0.w;
        x[4] = v1.x; x[5] = v1.y; x[6] = v1.z; x[7] = v1.w;
    } else {
#pragma unroll
        for (int e = 0; e < 8; ++e) {
            int d = d0 + e;
            x[e] = (d < Kin) ? src[(long)m * Kin + d] : 0.0f;
        }
    }
    unsigned short h8[8], l8[8];
#pragma unroll
    for (int e = 0; e < 8; ++e) {
        __hip_bfloat16 h = __float2bfloat16(x[e]);
        float hf = __bfloat162float(h);
        __hip_bfloat16 lv = __float2bfloat16(x[e] - hf);
        h8[e] = *(unsigned short*)&h;
        l8[e] = *(unsigned short*)&lv;
    }
    long ob = (long)m * Kout + d0;
    *(uint4*)(hi + ob) = *(uint4*)h8;
    *(uint4*)(lo + ob) = *(uint4*)l8;
}

// ---------------------------------------------------------------------------
// Kernel B: split-bf16 GEMM (round-1 version verbatim — 329 us, MfmaUtil 37%.
// Round-3's fused fp32-staging variant REGRESSED to 411 us: in-register hi/lo
// conversion sat on the LDS->MFMA critical path. Keep conversion out-of-line.)
// ---------------------------------------------------------------------------
__global__ __launch_bounds__(256, 2) void gemm_split(
    const unsigned short* __restrict__ Ahi, const unsigned short* __restrict__ Alo,
    const unsigned short* __restrict__ Bhi, const unsigned short* __restrict__ Blo,
    const float* __restrict__ bias, float* __restrict__ C)
{
    __shared__ __align__(16) unsigned short sAh[128 * 32];
    __shared__ __align__(16) unsigned short sAl[128 * 32];
    __shared__ __align__(16) unsigned short sBh[128 * 32];
    __shared__ __align__(16) unsigned short sBl[128 * 32];

    const int t    = threadIdx.x;
    const int nblk = blockIdx.x;   // 0..7   (N fastest -> A-tile reuse in L2/L3)
    const int mblk = blockIdx.y;   // 0..499
    const int wave = t >> 6, lane = t & 63;
    const int wr = wave >> 1, wc = wave & 1;

    f32x4 acc[4][4];
#pragma unroll
    for (int i = 0; i < 4; ++i)
#pragma unroll
        for (int j = 0; j < 4; ++j) acc[i][j] = (f32x4){0.f, 0.f, 0.f, 0.f};

    const long arow = (long)(mblk * 128 + (t >> 2)) * KP + (t & 3) * 8;
    const long brow = (long)(nblk * 128 + (t >> 2)) * KP + (t & 3) * 8;
    const int  l8   = t * 8;

    const int fr = lane & 15;
    const int fk = (lane >> 4) * 8;

    for (int ks = 0; ks < KP; ks += 32) {
        __syncthreads();
        gl_lds16(Ahi + arow + ks, &sAh[l8]);
        gl_lds16(Ahi + arow + 64 * KP + ks, &sAh[2048 + l8]);
        gl_lds16(Alo + arow + ks, &sAl[l8]);
        gl_lds16(Alo + arow + 64 * KP + ks, &sAl[2048 + l8]);
        gl_lds16(Bhi + brow + ks, &sBh[l8]);
        gl_lds16(Bhi + brow + 64 * KP + ks, &sBh[2048 + l8]);
        gl_lds16(Blo + brow + ks, &sBl[l8]);
        gl_lds16(Blo + brow + 64 * KP + ks, &sBl[2048 + l8]);
        __syncthreads();

        bf16x8 ah[4], al[4], bh[4], bl[4];
#pragma unroll
        for (int i = 0; i < 4; ++i) {
            ah[i] = *(const bf16x8*)&sAh[(wr * 64 + i * 16 + fr) * 32 + fk];
            al[i] = *(const bf16x8*)&sAl[(wr * 64 + i * 16 + fr) * 32 + fk];
            bh[i] = *(const bf16x8*)&sBh[(wc * 64 + i * 16 + fr) * 32 + fk];
            bl[i] = *(const bf16x8*)&sBl[(wc * 64 + i * 16 + fr) * 32 + fk];
        }
#pragma unroll
        for (int i = 0; i < 4; ++i)
#pragma unroll
            for (int j = 0; j < 4; ++j)
                acc[i][j] = __builtin_amdgcn_mfma_f32_16x16x32_bf16(ah[i], bh[j], acc[i][j], 0, 0, 0);
#pragma unroll
        for (int i = 0; i < 4; ++i)
#pragma unroll
            for (int j = 0; j < 4; ++j)
                acc[i][j] = __builtin_amdgcn_mfma_f32_16x16x32_bf16(ah[i], bl[j], acc[i][j], 0, 0, 0);
#pragma unroll
        for (int i = 0; i < 4; ++i)
#pragma unroll
            for (int j = 0; j < 4; ++j)
                acc[i][j] = __builtin_amdgcn_mfma_f32_16x16x32_bf16(al[i], bh[j], acc[i][j], 0, 0, 0);
    }

    const int r0 = mblk * 128 + wr * 64 + (lane >> 4) * 4;
    const int c0 = nblk * 128 + wc * 64 + (lane & 15);
#pragma unroll
    for (int j = 0; j < 4; ++j) {
        int col = c0 + j * 16;
        float bv = bias[col];
#pragma unroll
        for (int i = 0; i < 4; ++i) {
            int row = r0 + i * 16;
#pragma unroll
            for (int r = 0; r < 4; ++r)
                C[(long)(row + r) * H_ + col] = acc[i][j][r] + bv;
        }
    }
}

// ---------------------------------------------------------------------------
// Kernel C1: layer-1 LIF scan — the ONLY true nonlinear recurrence.
// Parallel over all 262k neurons (b,h); no barriers, no reductions.
// Spikes bit-packed: word widx = h>>6, bit = h&63, via __ballot.
// ---------------------------------------------------------------------------
__global__ __launch_bounds__(256) void lif_spikes(
    const float* __restrict__ d1,    // [B*T, H]
    const float* __restrict__ tau1,
    unsigned long long* __restrict__ spk)  // [B*T, 16]
{
    const int b    = blockIdx.y;
    const int h    = blockIdx.x * 256 + threadIdx.x;
    const int lane = threadIdx.x & 63;
    const int widx = blockIdx.x * 4 + (threadIdx.x >> 6);

    float tv  = tau1[h];
    float a1  = 1.0f / (1.0f + __expf(-tv));
    float om1 = 1.0f - a1;
    float mem = 0.f, sp = 0.f;

    const float* dp = d1 + (long)b * T_ * H_ + h;
    unsigned long long* op = spk + (long)b * T_ * 16 + widx;

    // 4-deep prefetch ring (branchless clamp)
    float p0 = dp[0], p1 = dp[1L * H_], p2 = dp[2L * H_], p3 = dp[3L * H_];

    for (int ts = 0; ts < T_; ++ts) {
        float cur = p0; p0 = p1; p1 = p2; p2 = p3;
        int nts = ts + 4; nts = (nts < T_) ? nts : (T_ - 1);
        p3 = dp[(long)nts * H_];

        mem = mem * a1 + om1 * cur - sp;
        sp  = (mem > 1.0f) ? 1.0f : 0.0f;
        unsigned long long msk = __ballot(mem > 1.0f);
        if (lane == 0) op[(long)ts * 16] = msk;
    }
}

// ---------------------------------------------------------------------------
// Kernel C2: d2 dots for ALL rows (parallel — reduce latency pipelines across
// independent rows). Block handles 64 rows; wave w = outputs 5w..5w+4; lane
// owns 16 W2 columns in registers. Output layout (o, ts, b) for C3 coalescing.
// ---------------------------------------------------------------------------
__global__ __launch_bounds__(256) void readout_dots(
    const unsigned long long* __restrict__ spk,  // [M_, 16]
    const float* __restrict__ W2,                // [O_, H_]
    float* __restrict__ d2t)                     // [O_][T_*256] idx o*M_+ts*256+b
{
    const int t = threadIdx.x, wave = t >> 6, lane = t & 63;

    float w2r[5][16];
#pragma unroll
    for (int oo = 0; oo < 5; ++oo)
#pragma unroll
        for (int q = 0; q < 4; ++q)
            *(float4*)&w2r[oo][4 * q] =
                *(const float4*)&W2[(wave * 5 + oo) * H_ + lane * 16 + 4 * q];

    const int rbase = blockIdx.x * 64;
    for (int i = 0; i < 64; ++i) {
        int r = rbase + i;                       // M_ = 1000*64 exactly
        unsigned long long bw = spk[(long)r * 16 + (lane >> 2)];
        unsigned int bits = (unsigned int)(bw >> ((lane & 3) * 16)) & 0xFFFFu;
        float pa[5] = {0.f, 0.f, 0.f, 0.f, 0.f};
#pragma unroll
        for (int j = 0; j < 16; ++j) {
            float f = (bits >> j) & 1u ? 1.0f : 0.0f;
#pragma unroll
            for (int oo = 0; oo < 5; ++oo)
                pa[oo] = fmaf(f, w2r[oo][j], pa[oo]);
        }
#pragma unroll
        for (int m = 1; m < 64; m <<= 1)
#pragma unroll
            for (int oo = 0; oo < 5; ++oo)
                pa[oo] += __shfl_xor(pa[oo], m, 64);
        if (lane == 0) {
            int b  = r / T_;
            int ts = r - b * T_;
#pragma unroll
            for (int oo = 0; oo < 5; ++oo)
                d2t[(long)(wave * 5 + oo) * M_ + ts * 256 + b] = pa[oo];
        }
    }
}

// ---------------------------------------------------------------------------
// Kernel C3: mem2 linear recurrence — per-(o,b) thread, coalesced over b.
// 250 dependent FMAs per thread; trivially fast.
// ---------------------------------------------------------------------------
__global__ __launch_bounds__(256) void mem2_scan(
    const float* __restrict__ d2t,   // (o, ts, b)
    const float* __restrict__ tau2, const float* __restrict__ b2,
    float* __restrict__ m2t)         // (o, ts, b)
{
    const int o = blockIdx.x;        // 0..19
    const int b = threadIdx.x;       // 0..255
    float tv  = tau2[o];
    float a2  = 1.0f / (1.0f + __expf(-tv));
    float om2 = 1.0f - a2;
    float bv  = b2[o];

    const float* dp = d2t + (long)o * M_ + b;
    float*       mp = m2t + (long)o * M_ + b;
    float mem = 0.f;

    float p0 = dp[0], p1 = dp[256], p2 = dp[512], p3 = dp[768];
    for (int ts = 0; ts < T_; ++ts) {
        float cur = p0; p0 = p1; p1 = p2; p2 = p3;
        int nts = ts + 4; nts = (nts < T_) ? nts : (T_ - 1);
        p3 = dp[(long)nts * 256];
        mem = mem * a2 + om2 * (cur + bv);
        mp[(long)ts * 256] = mem;
    }
}

// ---------------------------------------------------------------------------
// Kernel C4: per-(b,ts) softmax fully in-register + per-b sum over ts via LDS.
// ---------------------------------------------------------------------------
__global__ __launch_bounds__(256) void softmax_acc(
    const float* __restrict__ m2t,   // (o, ts, b)
    float* __restrict__ out)         // [B_, O_]
{
    __shared__ float sp[T_][O_];     // 19.5 KB
    const int b  = blockIdx.x;
    const int ts = threadIdx.x;

    if (ts < T_) {
        if (ts > 10) {
            float m[O_];
#pragma unroll
            for (int o = 0; o < O_; ++o)
                m[o] = m2t[(long)o * M_ + ts * 256 + b];
            float mx = m[0];
#pragma unroll
            for (int o = 1; o < O_; ++o) mx = fmaxf(mx, m[o]);
            float s = 0.f;
#pragma unroll
            for (int o = 0; o < O_; ++o) { m[o] = __expf(m[o] - mx); s += m[o]; }
            float inv = 1.0f / s;
#pragma unroll
            for (int o = 0; o < O_; ++o) sp[ts][o] = m[o] * inv;
        } else {
#pragma unroll
            for (int o = 0; o < O_; ++o) sp[ts][o] = 0.f;
        }
    }
    __syncthreads();
    if (ts < O_) {
        float s = 0.f;
        for (int k = 11; k < T_; ++k) s += sp[k][ts];
        out[b * O_ + ts] = s;
    }
}

// ---------------------------------------------------------------------------
extern "C" void kernel_launch(void* const* d_in, const int* in_sizes, int n_in,
                              void* d_out, int out_size, void* d_ws, size_t ws_size,
                              hipStream_t stream)
{
    const float* X    = (const float*)d_in[0];   // [B,T,D]
    const float* W1   = (const float*)d_in[1];   // [H,D]
    const float* b1   = (const float*)d_in[2];   // [H]
    const float* tau1 = (const float*)d_in[3];   // [H]
    const float* W2   = (const float*)d_in[4];   // [O,H]
    const float* b2   = (const float*)d_in[5];   // [O]
    const float* tau2 = (const float*)d_in[6];   // [O]
    float* out = (float*)d_out;

    // workspace layout (same footprint as round 1, ~445 MB):
    //   [Xhi 90MB][Xlo 90MB][W1hi][W1lo][d1 262MB]
    // aliases (stream-ordered, producers/consumers strictly sequential):
    //   spk  -> Xhi region (X consumed by gemm before lif_spikes writes)
    //   d2t/m2t -> Xlo region
    unsigned short* Xhi  = (unsigned short*)d_ws;
    unsigned short* Xlo  = Xhi + (long)M_ * KP;
    unsigned short* W1hi = Xlo + (long)M_ * KP;
    unsigned short* W1lo = W1hi + (long)H_ * KP;
    float* d1 = (float*)(W1lo + (long)H_ * KP);  // [M_, H] fp32

    unsigned long long* spk = (unsigned long long*)Xhi;      // 8.2 MB
    float* d2t = (float*)Xlo;                                // 5.1 MB
    float* m2t = d2t + (long)O_ * M_;                        // 5.1 MB

    // 1. split conversions (out-of-line: round-3 fusion regressed)
    {
        int chunks = M_ * (KP / 8);
        split_convert<<<(chunks + 255) / 256, 256, 0, stream>>>(X, Xhi, Xlo, M_, D_, KP);
    }
    {
        int chunks = H_ * (KP / 8);
        split_convert<<<(chunks + 255) / 256, 256, 0, stream>>>(W1, W1hi, W1lo, H_, D_, KP);
    }

    // 2. d1 = X @ W1^T + b1
    {
        dim3 grid(H_ / 128, M_ / 128);           // (8, 500)
        gemm_split<<<grid, 256, 0, stream>>>(Xhi, Xlo, W1hi, W1lo, b1, d1);
    }

    // 3. layer-1 spike scan (parallel over neurons)
    {
        dim3 grid(H_ / 256, B_);                 // (4, 256)
        lif_spikes<<<grid, 256, 0, stream>>>(d1, tau1, spk);
    }

    // 4. readout dots for all rows (parallel)
    readout_dots<<<M_ / 64, 256, 0, stream>>>(spk, W2, d2t);

    // 5. mem2 linear scan (parallel over (o,b))
    mem2_scan<<<O_, 256, 0, stream>>>(d2t, tau2, b2, m2t);

    // 6. softmax + accumulate
    softmax_acc<<<B_, 256, 0, stream>>>(m2t, out);
}

// Round 5
// 798.199 us; speedup vs baseline: 1.1182x; 1.0114x over previous
//
#include <hip/hip_runtime.h>
#include <hip/hip_bf16.h>

// Problem dims (fixed by reference)
#define B_  256
#define T_  250
#define D_  700
#define H_  1024
#define O_  20
#define KP  704          // K padded to multiple of 32 (22 K-steps of BK=32)
#define M_  64000        // B_*T_

typedef __attribute__((ext_vector_type(8))) short bf16x8;
typedef __attribute__((ext_vector_type(4))) float f32x4;

// async global->LDS, 16B per lane (LDS dest = wave-uniform base + lane*16)
__device__ __forceinline__ void gl_lds16(const void* g, void* l) {
    __builtin_amdgcn_global_load_lds(
        (const __attribute__((address_space(1))) unsigned int*)g,
        (__attribute__((address_space(3))) unsigned int*)l, 16, 0, 0);
}

// ---------------------------------------------------------------------------
// Kernel A: split fp32 -> bf16 hi/lo, zero-padding K from Kin to Kout.
// ---------------------------------------------------------------------------
__global__ void split_convert(const float* __restrict__ src,
                              unsigned short* __restrict__ hi,
                              unsigned short* __restrict__ lo,
                              int M, int Kin, int Kout)
{
    int idx = blockIdx.x * blockDim.x + threadIdx.x;
    int chunks = Kout >> 3;
    int total = M * chunks;
    if (idx >= total) return;
    int m  = idx / chunks;
    int c  = idx - m * chunks;
    int d0 = c << 3;
    float x[8];
    if (d0 + 8 <= Kin) {
        const float4* p = (const float4*)(src + (long)m * Kin + d0);
        float4 v0 = p[0], v1 = p[1];
        x[0] = v0.x; x[1] = v0.y; x[2] = v0.z; x[3] = v0.w;
        x[4] = v1.x; x[5] = v1.y; x[6] = v1.z; x[7] = v1.w;
    } else {
#pragma unroll
        for (int e = 0; e < 8; ++e) {
            int d = d0 + e;
            x[e] = (d < Kin) ? src[(long)m * Kin + d] : 0.0f;
        }
    }
    unsigned short h8[8], l8[8];
#pragma unroll
    for (int e = 0; e < 8; ++e) {
        __hip_bfloat16 h = __float2bfloat16(x[e]);
        float hf = __bfloat162float(h);
        __hip_bfloat16 lv = __float2bfloat16(x[e] - hf);
        h8[e] = *(unsigned short*)&h;
        l8[e] = *(unsigned short*)&lv;
    }
    long ob = (long)m * Kout + d0;
    *(uint4*)(hi + ob) = *(uint4*)h8;
    *(uint4*)(lo + ob) = *(uint4*)l8;
}

// ---------------------------------------------------------------------------
// Kernel B: split-bf16 GEMM. Round-5 change: fragment loads restructured to
// shrink live VGPRs (B-frags up front = 32 regs, A-frags loaded per-i = 8
// live vs 32) + __launch_bounds__(256,4) targeting 4 blocks/CU (was 3 at
// 72 VGPR + 64 AGPR = 136 unified). Per-acc MFMA reuse distance kept at 4
// by interleaving the three passes inside the i-loop.
// ---------------------------------------------------------------------------
__global__ __launch_bounds__(256, 4) void gemm_split(
    const unsigned short* __restrict__ Ahi, const unsigned short* __restrict__ Alo,
    const unsigned short* __restrict__ Bhi, const unsigned short* __restrict__ Blo,
    const float* __restrict__ bias, float* __restrict__ C)
{
    __shared__ __align__(16) unsigned short sAh[128 * 32];
    __shared__ __align__(16) unsigned short sAl[128 * 32];
    __shared__ __align__(16) unsigned short sBh[128 * 32];
    __shared__ __align__(16) unsigned short sBl[128 * 32];

    const int t    = threadIdx.x;
    const int nblk = blockIdx.x;   // 0..7
    const int mblk = blockIdx.y;   // 0..499
    const int wave = t >> 6, lane = t & 63;
    const int wr = wave >> 1, wc = wave & 1;

    f32x4 acc[4][4];
#pragma unroll
    for (int i = 0; i < 4; ++i)
#pragma unroll
        for (int j = 0; j < 4; ++j) acc[i][j] = (f32x4){0.f, 0.f, 0.f, 0.f};

    const long arow = (long)(mblk * 128 + (t >> 2)) * KP + (t & 3) * 8;
    const long brow = (long)(nblk * 128 + (t >> 2)) * KP + (t & 3) * 8;
    const int  l8   = t * 8;

    const int fr = lane & 15;
    const int fk = (lane >> 4) * 8;

    for (int ks = 0; ks < KP; ks += 32) {
        __syncthreads();
        gl_lds16(Ahi + arow + ks, &sAh[l8]);
        gl_lds16(Ahi + arow + 64 * KP + ks, &sAh[2048 + l8]);
        gl_lds16(Alo + arow + ks, &sAl[l8]);
        gl_lds16(Alo + arow + 64 * KP + ks, &sAl[2048 + l8]);
        gl_lds16(Bhi + brow + ks, &sBh[l8]);
        gl_lds16(Bhi + brow + 64 * KP + ks, &sBh[2048 + l8]);
        gl_lds16(Blo + brow + ks, &sBl[l8]);
        gl_lds16(Blo + brow + 64 * KP + ks, &sBl[2048 + l8]);
        __syncthreads();

        // B fragments resident across the i-loop (32 VGPRs)
        bf16x8 bh[4], bl[4];
#pragma unroll
        for (int j = 0; j < 4; ++j) {
            bh[j] = *(const bf16x8*)&sBh[(wc * 64 + j * 16 + fr) * 32 + fk];
            bl[j] = *(const bf16x8*)&sBl[(wc * 64 + j * 16 + fr) * 32 + fk];
        }
        // A fragments loaded per-i (8 VGPRs live instead of 32)
#pragma unroll
        for (int i = 0; i < 4; ++i) {
            bf16x8 ah = *(const bf16x8*)&sAh[(wr * 64 + i * 16 + fr) * 32 + fk];
            bf16x8 al = *(const bf16x8*)&sAl[(wr * 64 + i * 16 + fr) * 32 + fk];
#pragma unroll
            for (int j = 0; j < 4; ++j)
                acc[i][j] = __builtin_amdgcn_mfma_f32_16x16x32_bf16(ah, bh[j], acc[i][j], 0, 0, 0);
#pragma unroll
            for (int j = 0; j < 4; ++j)
                acc[i][j] = __builtin_amdgcn_mfma_f32_16x16x32_bf16(ah, bl[j], acc[i][j], 0, 0, 0);
#pragma unroll
            for (int j = 0; j < 4; ++j)
                acc[i][j] = __builtin_amdgcn_mfma_f32_16x16x32_bf16(al, bh[j], acc[i][j], 0, 0, 0);
        }
    }

    const int r0 = mblk * 128 + wr * 64 + (lane >> 4) * 4;
    const int c0 = nblk * 128 + wc * 64 + (lane & 15);
#pragma unroll
    for (int j = 0; j < 4; ++j) {
        int col = c0 + j * 16;
        float bv = bias[col];
#pragma unroll
        for (int i = 0; i < 4; ++i) {
            int row = r0 + i * 16;
#pragma unroll
            for (int r = 0; r < 4; ++r)
                C[(long)(row + r) * H_ + col] = acc[i][j][r] + bv;
        }
    }
}

// ---------------------------------------------------------------------------
// Kernel C1: layer-1 LIF scan. Ring depth 6 (was 4): outstanding-load
// budget 27 B/cyc/CU vs the 10 needed for HBM-rate streaming.
// ---------------------------------------------------------------------------
__global__ __launch_bounds__(256) void lif_spikes(
    const float* __restrict__ d1,    // [B*T, H]
    const float* __restrict__ tau1,
    unsigned long long* __restrict__ spk)  // [B*T, 16]
{
    const int b    = blockIdx.y;
    const int h    = blockIdx.x * 256 + threadIdx.x;
    const int lane = threadIdx.x & 63;
    const int widx = blockIdx.x * 4 + (threadIdx.x >> 6);

    float tv  = tau1[h];
    float a1  = 1.0f / (1.0f + __expf(-tv));
    float om1 = 1.0f - a1;
    float mem = 0.f, sp = 0.f;

    const float* dp = d1 + (long)b * T_ * H_ + h;
    unsigned long long* op = spk + (long)b * T_ * 16 + widx;

    float p0 = dp[0],        p1 = dp[1L * H_], p2 = dp[2L * H_];
    float p3 = dp[3L * H_],  p4 = dp[4L * H_], p5 = dp[5L * H_];

    for (int ts = 0; ts < T_; ++ts) {
        float cur = p0;
        p0 = p1; p1 = p2; p2 = p3; p3 = p4; p4 = p5;
        int nts = ts + 6; nts = (nts < T_) ? nts : (T_ - 1);
        p5 = dp[(long)nts * H_];

        mem = mem * a1 + om1 * cur - sp;
        sp  = (mem > 1.0f) ? 1.0f : 0.0f;
        unsigned long long msk = __ballot(mem > 1.0f);
        if (lane == 0) op[(long)ts * 16] = msk;
    }
}

// ---------------------------------------------------------------------------
// Kernel C2: d2 dots. Round-5: 2000 blocks x 32 rows, 2-row ILP so the
// 6-stage shuffle-reduce chains of two rows pipeline instead of serializing.
// ---------------------------------------------------------------------------
__global__ __launch_bounds__(256) void readout_dots(
    const unsigned long long* __restrict__ spk,  // [M_, 16]
    const float* __restrict__ W2,                // [O_, H_]
    float* __restrict__ d2t)                     // idx o*M_ + ts*256 + b
{
    const int t = threadIdx.x, wave = t >> 6, lane = t & 63;

    float w2r[5][16];
#pragma unroll
    for (int oo = 0; oo < 5; ++oo)
#pragma unroll
        for (int q = 0; q < 4; ++q)
            *(float4*)&w2r[oo][4 * q] =
                *(const float4*)&W2[(wave * 5 + oo) * H_ + lane * 16 + 4 * q];

    const int rbase = blockIdx.x * 32;           // M_ = 2000*32
    int b0 = rbase / T_;
    int ts0 = rbase - b0 * T_;

    for (int i = 0; i < 32; i += 2) {
        int r0 = rbase + i, r1 = r0 + 1;
        unsigned long long bw0 = spk[(long)r0 * 16 + (lane >> 2)];
        unsigned long long bw1 = spk[(long)r1 * 16 + (lane >> 2)];
        unsigned int bits0 = (unsigned int)(bw0 >> ((lane & 3) * 16)) & 0xFFFFu;
        unsigned int bits1 = (unsigned int)(bw1 >> ((lane & 3) * 16)) & 0xFFFFu;
        float pa0[5] = {0, 0, 0, 0, 0}, pa1[5] = {0, 0, 0, 0, 0};
#pragma unroll
        for (int j = 0; j < 16; ++j) {
            float f0 = (bits0 >> j) & 1u ? 1.0f : 0.0f;
            float f1 = (bits1 >> j) & 1u ? 1.0f : 0.0f;
#pragma unroll
            for (int oo = 0; oo < 5; ++oo) {
                pa0[oo] = fmaf(f0, w2r[oo][j], pa0[oo]);
                pa1[oo] = fmaf(f1, w2r[oo][j], pa1[oo]);
            }
        }
#pragma unroll
        for (int m = 1; m < 64; m <<= 1)
#pragma unroll
            for (int oo = 0; oo < 5; ++oo) {
                pa0[oo] += __shfl_xor(pa0[oo], m, 64);
                pa1[oo] += __shfl_xor(pa1[oo], m, 64);
            }
        if (lane == 0) {
            int bA = b0, tsA = ts0 + i;
            if (tsA >= T_) { tsA -= T_; bA += 1; }   // rbase%2==0, i even: safe
            int bB = bA, tsB = tsA + 1;
            if (tsB >= T_) { tsB = 0; bB += 1; }
#pragma unroll
            for (int oo = 0; oo < 5; ++oo) {
                d2t[(long)(wave * 5 + oo) * M_ + tsA * 256 + bA] = pa0[oo];
                d2t[(long)(wave * 5 + oo) * M_ + tsB * 256 + bB] = pa1[oo];
            }
        }
    }
}

// ---------------------------------------------------------------------------
// Kernel C3: mem2 linear recurrence. Round-5: grid (20 o x 4 b-chunks),
// 64-thread blocks -> 80 blocks (was 20).
// ---------------------------------------------------------------------------
__global__ __launch_bounds__(64) void mem2_scan(
    const float* __restrict__ d2t,   // (o, ts, b)
    const float* __restrict__ tau2, const float* __restrict__ b2,
    float* __restrict__ m2t)         // (o, ts, b)
{
    const int o = blockIdx.x;                    // 0..19
    const int b = blockIdx.y * 64 + threadIdx.x; // 0..255
    float tv  = tau2[o];
    float a2  = 1.0f / (1.0f + __expf(-tv));
    float om2 = 1.0f - a2;
    float bv  = b2[o];

    const float* dp = d2t + (long)o * M_ + b;
    float*       mp = m2t + (long)o * M_ + b;
    float mem = 0.f;

    float p0 = dp[0], p1 = dp[256], p2 = dp[512], p3 = dp[768];
    for (int ts = 0; ts < T_; ++ts) {
        float cur = p0; p0 = p1; p1 = p2; p2 = p3;
        int nts = ts + 4; nts = (nts < T_) ? nts : (T_ - 1);
        p3 = dp[(long)nts * 256];
        mem = mem * a2 + om2 * (cur + bv);
        mp[(long)ts * 256] = mem;
    }
}

// ---------------------------------------------------------------------------
// Kernel C4: per-(b,ts) softmax in-register + per-b sum over ts via LDS.
// ---------------------------------------------------------------------------
__global__ __launch_bounds__(256) void softmax_acc(
    const float* __restrict__ m2t,   // (o, ts, b)
    float* __restrict__ out)         // [B_, O_]
{
    __shared__ float sp[T_][O_];     // 19.5 KB
    const int b  = blockIdx.x;
    const int ts = threadIdx.x;

    if (ts < T_) {
        if (ts > 10) {
            float m[O_];
#pragma unroll
            for (int o = 0; o < O_; ++o)
                m[o] = m2t[(long)o * M_ + ts * 256 + b];
            float mx = m[0];
#pragma unroll
            for (int o = 1; o < O_; ++o) mx = fmaxf(mx, m[o]);
            float s = 0.f;
#pragma unroll
            for (int o = 0; o < O_; ++o) { m[o] = __expf(m[o] - mx); s += m[o]; }
            float inv = 1.0f / s;
#pragma unroll
            for (int o = 0; o < O_; ++o) sp[ts][o] = m[o] * inv;
        } else {
#pragma unroll
            for (int o = 0; o < O_; ++o) sp[ts][o] = 0.f;
        }
    }
    __syncthreads();
    if (ts < O_) {
        float s = 0.f;
        for (int k = 11; k < T_; ++k) s += sp[k][ts];
        out[b * O_ + ts] = s;
    }
}

// ---------------------------------------------------------------------------
extern "C" void kernel_launch(void* const* d_in, const int* in_sizes, int n_in,
                              void* d_out, int out_size, void* d_ws, size_t ws_size,
                              hipStream_t stream)
{
    const float* X    = (const float*)d_in[0];
    const float* W1   = (const float*)d_in[1];
    const float* b1   = (const float*)d_in[2];
    const float* tau1 = (const float*)d_in[3];
    const float* W2   = (const float*)d_in[4];
    const float* b2   = (const float*)d_in[5];
    const float* tau2 = (const float*)d_in[6];
    float* out = (float*)d_out;

    unsigned short* Xhi  = (unsigned short*)d_ws;
    unsigned short* Xlo  = Xhi + (long)M_ * KP;
    unsigned short* W1hi = Xlo + (long)M_ * KP;
    unsigned short* W1lo = W1hi + (long)H_ * KP;
    float* d1 = (float*)(W1lo + (long)H_ * KP);  // [M_, H] fp32

    unsigned long long* spk = (unsigned long long*)Xhi;      // aliases X splits
    float* d2t = (float*)Xlo;                                // (safe: sequential)
    float* m2t = d2t + (long)O_ * M_;

    // 1. split conversions
    {
        int chunks = M_ * (KP / 8);
        split_convert<<<(chunks + 255) / 256, 256, 0, stream>>>(X, Xhi, Xlo, M_, D_, KP);
    }
    {
        int chunks = H_ * (KP / 8);
        split_convert<<<(chunks + 255) / 256, 256, 0, stream>>>(W1, W1hi, W1lo, H_, D_, KP);
    }

    // 2. d1 = X @ W1^T + b1
    {
        dim3 grid(H_ / 128, M_ / 128);           // (8, 500)
        gemm_split<<<grid, 256, 0, stream>>>(Xhi, Xlo, W1hi, W1lo, b1, d1);
    }

    // 3. layer-1 spike scan
    {
        dim3 grid(H_ / 256, B_);                 // (4, 256)
        lif_spikes<<<grid, 256, 0, stream>>>(d1, tau1, spk);
    }

    // 4. readout dots
    readout_dots<<<M_ / 32, 256, 0, stream>>>(spk, W2, d2t);

    // 5. mem2 linear scan
    {
        dim3 grid(O_, 4);
        mem2_scan<<<grid, 64, 0, stream>>>(d2t, tau2, b2, m2t);
    }

    // 6. softmax + accumulate
    softmax_acc<<<B_, 256, 0, stream>>>(m2t, out);
}